// Round 1
// baseline (448.613 us; speedup 1.0000x reference)
//
#include <hip/hip_runtime.h>
#include <stdint.h>

// Sizes fixed by the reference problem.
static constexpr int Bn = 4096;
static constexpr int Dn = 5000;
static constexpr int Hn = 2000;
static constexpr int Ln = 50;
static constexpr int XW = 80;   // u64 words per D-length bit row (ceil(5000/64)=79, pad to 80)
static constexpr int ZW = 32;   // u64 words per H-length bit row (ceil(2000/64)=31.25 -> 32)

__device__ __forceinline__ int popc_acc(uint64_t v, int acc) {
  // v_bcnt_u32_b32 has a fused "+S1" accumulate; write it so LLVM can fold.
  acc = __builtin_popcount((uint32_t)v) + acc;
  acc = __builtin_popcount((uint32_t)(v >> 32)) + acc;
  return acc;
}

// One wave per (row, word): pack (src[row][col] >= 0.5) into 64-bit words via ballot.
__global__ void k_pack_rows(const float* __restrict__ src, uint64_t* __restrict__ dst,
                            int nrows, int ncols, int nwords) {
  int g = (int)((blockIdx.x * blockDim.x + threadIdx.x) >> 6);
  int lane = (int)(threadIdx.x & 63);
  int row = g / nwords;
  int word = g - row * nwords;
  if (row >= nrows) return;
  int col = (word << 6) + lane;
  float v = (col < ncols) ? src[(size_t)row * ncols + col] : 0.0f;
  unsigned long long m = __ballot(v >= 0.5f);
  if (lane == 0) dst[(size_t)row * nwords + word] = m;
}

// Column bitsets of Wb: wtbits[d][w] bit k = (W[(w*64+k)][d] >= 0.5).
// Consecutive waves take consecutive d so strided lane loads share cache lines.
__global__ void k_pack_wcols(const float* __restrict__ W, uint64_t* __restrict__ dst) {
  int g = (int)((blockIdx.x * blockDim.x + threadIdx.x) >> 6);
  int lane = (int)(threadIdx.x & 63);
  int w = g / Dn;
  int d = g - w * Dn;
  if (w >= ZW) return;
  int j = (w << 6) + lane;
  float v = (j < Hn) ? W[(size_t)j * Dn + d] : 0.0f;
  unsigned long long m = __ballot(v >= 0.5f);
  if (lane == 0) dst[(size_t)d * ZW + w] = m;
}

// fwT[j][l] = sigmoid(2 * cw[l][j]), padded to 64 cols (pad = 0) for coalesced lane loads.
__global__ void k_pack_fwT(const float* __restrict__ cw, float* __restrict__ fwT) {
  int idx = blockIdx.x * blockDim.x + threadIdx.x;
  if (idx >= Hn * 64) return;
  int j = idx >> 6, l = idx & 63;
  float v = 0.0f;
  if (l < Ln) {
    float t = 2.0f * cw[(size_t)l * Hn + j];
    v = 1.0f / (1.0f + expf(-t));
  }
  fwT[idx] = v;
}

__global__ void k_zero(float* __restrict__ p, int n) {
  int i = blockIdx.x * blockDim.x + threadIdx.x;
  if (i < n) p[i] = 0.0f;
}

// h = popcount(xbits & wbits) (exact int), z = ((h + b_enc) + act0_bias >= 1).
// Writes z as float to d_out and z bitsets (via ballot) for the decoder.
// TB=8 batch rows per thread amortize the per-j weight-word load.
__global__ __launch_bounds__(256) void k_enc(const uint64_t* __restrict__ xbits,
                                             const uint64_t* __restrict__ wbits,
                                             const float* __restrict__ b_enc,
                                             const float* __restrict__ act0_bias,
                                             float* __restrict__ z_out,
                                             uint64_t* __restrict__ zbits) {
  constexpr int TB = 8;
  int j = blockIdx.x * 256 + threadIdx.x;
  bool valid = j < Hn;
  int js = valid ? j : (Hn - 1);
  int b0 = blockIdx.y * TB;
  const uint64_t* wr = wbits + (size_t)js * XW;      // per-lane row
  const uint64_t* x0 = xbits + (size_t)b0 * XW;      // wave-uniform -> scalar loads
  int acc[TB] = {};
#pragma unroll 2
  for (int w = 0; w < XW; ++w) {
    uint64_t ww = wr[w];
#pragma unroll
    for (int i = 0; i < TB; ++i) acc[i] = popc_acc(x0[(size_t)i * XW + w] & ww, acc[i]);
  }
  float be = b_enc[js];
  float ab = act0_bias[js];
  int lane = (int)(threadIdx.x & 63);
  int word = j >> 6;  // wave-uniform (wave spans 64 consecutive j)
#pragma unroll
  for (int i = 0; i < TB; ++i) {
    float h = (float)acc[i] + be;   // exact: integer + fp32, matches reference order
    float zz = h + ab;
    bool zb = valid && (zz >= 1.0f);
    unsigned long long m = __ballot(zb);
    if (lane == 0) zbits[(size_t)(b0 + i) * ZW + word] = m;
    if (valid) z_out[(size_t)(b0 + i) * Hn + j] = zb ? 1.0f : 0.0f;
  }
}

// xd = popcount(zbits & wtbits) (exact int), output = (xd + act3_bias >= 1).
__global__ __launch_bounds__(256) void k_dec(const uint64_t* __restrict__ zbits,
                                             const uint64_t* __restrict__ wtbits,
                                             const float* __restrict__ act3_bias,
                                             float* __restrict__ out) {
  constexpr int TB = 8;
  int d = blockIdx.x * 256 + threadIdx.x;
  bool valid = d < Dn;
  int dsafe = valid ? d : (Dn - 1);
  int b0 = blockIdx.y * TB;
  const uint64_t* wt = wtbits + (size_t)dsafe * ZW;  // per-lane row
  const uint64_t* z0 = zbits + (size_t)b0 * ZW;      // wave-uniform -> scalar loads
  int acc[TB] = {};
#pragma unroll
  for (int w = 0; w < ZW; ++w) {
    uint64_t ww = wt[w];
#pragma unroll
    for (int i = 0; i < TB; ++i) acc[i] = popc_acc(z0[(size_t)i * ZW + w] & ww, acc[i]);
  }
  if (valid) {
    float ab = act3_bias[d];
#pragma unroll
    for (int i = 0; i < TB; ++i)
      out[(size_t)(b0 + i) * Dn + d] = ((float)acc[i] + ab >= 1.0f) ? 1.0f : 0.0f;
  }
}

// classification[b][l] = sum_j z[b][j] * fwT[j][l].
// One wave handles 8 batch rows x (1/8 of H); lane = l; partial sums via atomicAdd.
__global__ __launch_bounds__(256) void k_cls(const float* __restrict__ z,
                                             const float* __restrict__ fwT,
                                             float* __restrict__ cls) {
  constexpr int TB = 8, JSPLIT = 8, CH = Hn / JSPLIT;  // 250
  int gw = (int)((blockIdx.x * blockDim.x + threadIdx.x) >> 6);
  int lane = (int)(threadIdx.x & 63);
  int bq = __builtin_amdgcn_readfirstlane(gw / JSPLIT);
  int jc = __builtin_amdgcn_readfirstlane(gw - bq * JSPLIT);
  int b0 = bq * TB;
  float acc[TB];
#pragma unroll
  for (int i = 0; i < TB; ++i) acc[i] = 0.0f;
  const float* zp = z + (size_t)b0 * Hn + (size_t)jc * CH;  // uniform addresses -> s_load
  const float* fp = fwT + (size_t)jc * CH * 64 + lane;      // coalesced
#pragma unroll 4
  for (int t = 0; t < CH; ++t) {
    float fwv = fp[(size_t)t * 64];
#pragma unroll
    for (int i = 0; i < TB; ++i) acc[i] += zp[(size_t)i * Hn + t] * fwv;
  }
  if (lane < Ln) {
#pragma unroll
    for (int i = 0; i < TB; ++i)
      atomicAdd(&cls[(size_t)(b0 + i) * Ln + lane], acc[i]);
  }
}

extern "C" void kernel_launch(void* const* d_in, const int* in_sizes, int n_in,
                              void* d_out, int out_size, void* d_ws, size_t ws_size,
                              hipStream_t stream) {
  const float* x     = (const float*)d_in[0];  // [B][D]
  const float* W     = (const float*)d_in[1];  // [H][D]
  const float* b_enc = (const float*)d_in[2];  // [H]
  const float* act0b = (const float*)d_in[3];  // [H]
  const float* act3b = (const float*)d_in[4];  // [D]
  const float* cw    = (const float*)d_in[5];  // [L][H]

  float* out0 = (float*)d_out;              // output        [B][D]
  float* cls  = out0 + (size_t)Bn * Dn;     // classification[B][L]
  float* zout = cls + (size_t)Bn * Ln;      // z             [B][H]

  // Workspace layout (needs ~6.8 MB).
  char* ws = (char*)d_ws;
  uint64_t* xbits  = (uint64_t*)ws; ws += (size_t)Bn * XW * 8;  // 2.62 MB
  uint64_t* wbits  = (uint64_t*)ws; ws += (size_t)Hn * XW * 8;  // 1.28 MB
  uint64_t* wtbits = (uint64_t*)ws; ws += (size_t)Dn * ZW * 8;  // 1.28 MB
  uint64_t* zbits  = (uint64_t*)ws; ws += (size_t)Bn * ZW * 8;  // 1.05 MB
  float*    fwT    = (float*)ws;    ws += (size_t)Hn * 64 * 4;  // 0.51 MB

  {
    long long waves = (long long)Bn * XW;
    k_pack_rows<<<(int)((waves * 64 + 255) / 256), 256, 0, stream>>>(x, xbits, Bn, Dn, XW);
  }
  {
    long long waves = (long long)Hn * XW;
    k_pack_rows<<<(int)((waves * 64 + 255) / 256), 256, 0, stream>>>(W, wbits, Hn, Dn, XW);
  }
  {
    long long waves = (long long)ZW * Dn;
    k_pack_wcols<<<(int)((waves * 64 + 255) / 256), 256, 0, stream>>>(W, wtbits);
  }
  k_pack_fwT<<<(Hn * 64 + 255) / 256, 256, 0, stream>>>(cw, fwT);
  k_zero<<<(Bn * Ln + 255) / 256, 256, 0, stream>>>(cls, Bn * Ln);

  dim3 g1((Hn + 255) / 256, Bn / 8);
  k_enc<<<g1, 256, 0, stream>>>(xbits, wbits, b_enc, act0b, zout, zbits);

  k_cls<<<(Bn / 8) * 8 * 64 / 256, 256, 0, stream>>>(zout, fwT, cls);

  dim3 g2((Dn + 255) / 256, Bn / 8);
  k_dec<<<g2, 256, 0, stream>>>(zbits, wtbits, act3b, out0);
}

// Round 2
// 369.897 us; speedup vs baseline: 1.2128x; 1.2128x over previous
//
#include <hip/hip_runtime.h>
#include <stdint.h>

// Sizes fixed by the reference problem.
static constexpr int Bn = 4096;
static constexpr int Dn = 5000;
static constexpr int Hn = 2000;
static constexpr int Ln = 50;
static constexpr int XW = 80;   // u64 words per D-length bit row (ceil(5000/64)=79 -> pad 80)
static constexpr int ZW = 32;   // u64 words per H-length bit row (ceil(2000/64)=31.25 -> 32)

__device__ __forceinline__ int popc_acc(uint64_t v, int acc) {
  // v_bcnt_u32_b32 has fused "+S1" accumulate; written so LLVM folds it.
  acc = __builtin_popcount((uint32_t)v) + acc;
  acc = __builtin_popcount((uint32_t)(v >> 32)) + acc;
  return acc;
}

// Pack (src[row][col] >= 0.5) into u64 words, 4 words per wave.
// Output indexing: dst[(word)*sw + row*sr] — supports row-major (sw=1,sr=nwords)
// and transposed (sw=nrows_out_stride, sr=1) layouts.
__global__ void k_pack_rows4(const float* __restrict__ src, uint64_t* __restrict__ dst,
                             int nrows, int ncols, int nwords, int sw, int sr) {
  int g = (int)((blockIdx.x * blockDim.x + threadIdx.x) >> 6);
  int lane = (int)(threadIdx.x & 63);
  int nq = nwords >> 2;
  int row = g / nq;
  int q = g - row * nq;
  if (row >= nrows) return;
  int w0 = q << 2;
  unsigned long long m[4];
#pragma unroll
  for (int e = 0; e < 4; ++e) {
    int col = ((w0 + e) << 6) + lane;
    float v = (col < ncols) ? src[(size_t)row * ncols + col] : 0.0f;
    m[e] = __ballot(v >= 0.5f);
  }
  if (lane < 4) {
    unsigned long long mv = m[0];
    mv = (lane == 1) ? m[1] : mv;
    mv = (lane == 2) ? m[2] : mv;
    mv = (lane == 3) ? m[3] : mv;
    dst[(size_t)(w0 + lane) * sw + (size_t)row * sr] = mv;
  }
}

// Column bitsets of Wb: wtbits[d][w] bit k = (W[(w*64+k)][d] >= 0.5).
__global__ void k_pack_wcols(const float* __restrict__ W, uint64_t* __restrict__ dst) {
  int g = (int)((blockIdx.x * blockDim.x + threadIdx.x) >> 6);
  int lane = (int)(threadIdx.x & 63);
  int w = g / Dn;
  int d = g - w * Dn;
  if (w >= ZW) return;
  int j = (w << 6) + lane;
  float v = (j < Hn) ? W[(size_t)j * Dn + d] : 0.0f;
  unsigned long long m = __ballot(v >= 0.5f);
  if (lane == 0) dst[(size_t)d * ZW + w] = m;
}

// fwT[j][l] = sigmoid(2 * cw[l][j]), padded to 64 cols (pad = 0).
__global__ void k_pack_fwT(const float* __restrict__ cw, float* __restrict__ fwT) {
  int idx = blockIdx.x * blockDim.x + threadIdx.x;
  if (idx >= Hn * 64) return;
  int j = idx >> 6, l = idx & 63;
  float v = 0.0f;
  if (l < Ln) {
    float t = 2.0f * cw[(size_t)l * Hn + j];
    v = 1.0f / (1.0f + expf(-t));
  }
  fwT[idx] = v;
}

__global__ void k_zero(float* __restrict__ p, int n) {
  int i = blockIdx.x * blockDim.x + threadIdx.x;
  if (i < n) p[i] = 0.0f;
}

// h = popcount(x & w) exact; z = (h + b_enc + act0_bias >= 1).
// xbT is TRANSPOSED [XW][Bn] so the TB batch words per K-word are contiguous
// -> wide scalar (s_load_dwordx16) loads. Weight row is per-lane, loaded as ulong2.
__global__ __launch_bounds__(256) void k_enc(const uint64_t* __restrict__ xbT,
                                             const uint64_t* __restrict__ wbits,
                                             const float* __restrict__ b_enc,
                                             const float* __restrict__ act0_bias,
                                             float* __restrict__ z_out,
                                             uint64_t* __restrict__ zbT) {
  constexpr int TB = 16;
  int j = blockIdx.x * 256 + threadIdx.x;
  bool valid = j < Hn;
  int js = valid ? j : (Hn - 1);
  int b0 = blockIdx.y * TB;
  const ulong2* wr = (const ulong2*)(wbits + (size_t)js * XW);  // per-lane
  const uint64_t* xb = xbT + b0;                                 // wave-uniform
  int acc[TB] = {};
#pragma unroll 2
  for (int w2 = 0; w2 < XW / 2; ++w2) {
    ulong2 ww = wr[w2];
    const uint64_t* xa = xb + (size_t)(2 * w2) * Bn;
#pragma unroll
    for (int i = 0; i < TB; ++i) acc[i] = popc_acc(xa[i] & ww.x, acc[i]);
    const uint64_t* xc = xa + Bn;
#pragma unroll
    for (int i = 0; i < TB; ++i) acc[i] = popc_acc(xc[i] & ww.y, acc[i]);
  }
  float be = b_enc[js];
  float ab = act0_bias[js];
  int lane = (int)(threadIdx.x & 63);
  int word = j >> 6;  // wave-uniform (wave spans 64 consecutive j)
#pragma unroll
  for (int i = 0; i < TB; ++i) {
    float h = (float)acc[i] + be;  // exact: integer + fp32, matches reference order
    bool zb = valid && (h + ab >= 1.0f);
    unsigned long long m = __ballot(zb);
    if (lane == 0) zbT[(size_t)word * Bn + (b0 + i)] = m;
    if (valid) z_out[(size_t)(b0 + i) * Hn + j] = zb ? 1.0f : 0.0f;
  }
}

// xd = popcount(z & Wcol) exact; output = (xd + act3_bias >= 1).
// zbT is TRANSPOSED [ZW][Bn]; weight col row (wtbits[d]) per-lane as ulong2.
__global__ __launch_bounds__(256) void k_dec(const uint64_t* __restrict__ zbT,
                                             const uint64_t* __restrict__ wtbits,
                                             const float* __restrict__ act3_bias,
                                             float* __restrict__ out) {
  constexpr int TB = 16;
  int d = blockIdx.x * 256 + threadIdx.x;
  bool valid = d < Dn;
  int dsafe = valid ? d : (Dn - 1);
  int b0 = blockIdx.y * TB;
  const ulong2* wt = (const ulong2*)(wtbits + (size_t)dsafe * ZW);  // per-lane
  const uint64_t* zb = zbT + b0;                                    // wave-uniform
  int acc[TB] = {};
#pragma unroll 4
  for (int w2 = 0; w2 < ZW / 2; ++w2) {
    ulong2 ww = wt[w2];
    const uint64_t* za = zb + (size_t)(2 * w2) * Bn;
#pragma unroll
    for (int i = 0; i < TB; ++i) acc[i] = popc_acc(za[i] & ww.x, acc[i]);
    const uint64_t* zc = za + Bn;
#pragma unroll
    for (int i = 0; i < TB; ++i) acc[i] = popc_acc(zc[i] & ww.y, acc[i]);
  }
  if (valid) {
    float ab = act3_bias[d];
#pragma unroll
    for (int i = 0; i < TB; ++i)
      out[(size_t)(b0 + i) * Dn + d] = ((float)acc[i] + ab >= 1.0f) ? 1.0f : 0.0f;
  }
}

// classification[b][l] = sum_j z[b][j] * fwT[j][l].
// One wave: TB batch rows x (1/JSPLIT of H); lane = l; partials via atomicAdd.
__global__ __launch_bounds__(256) void k_cls(const float* __restrict__ z,
                                             const float* __restrict__ fwT,
                                             float* __restrict__ cls) {
  constexpr int TB = 4, JSPLIT = 16, CH = Hn / JSPLIT;  // 125
  int gw = (int)((blockIdx.x * blockDim.x + threadIdx.x) >> 6);
  int lane = (int)(threadIdx.x & 63);
  int bq = __builtin_amdgcn_readfirstlane(gw / JSPLIT);
  int jc = __builtin_amdgcn_readfirstlane(gw - bq * JSPLIT);
  int b0 = bq * TB;
  float acc[TB];
#pragma unroll
  for (int i = 0; i < TB; ++i) acc[i] = 0.0f;
  const float* zp = z + (size_t)b0 * Hn + (size_t)jc * CH;  // uniform -> scalar loads
  const float* fp = fwT + (size_t)jc * CH * 64 + lane;      // coalesced
#pragma unroll 5
  for (int t = 0; t < CH; ++t) {
    float fwv = fp[(size_t)t * 64];
#pragma unroll
    for (int i = 0; i < TB; ++i) acc[i] += zp[(size_t)i * Hn + t] * fwv;
  }
  if (lane < Ln) {
#pragma unroll
    for (int i = 0; i < TB; ++i)
      atomicAdd(&cls[(size_t)(b0 + i) * Ln + lane], acc[i]);
  }
}

extern "C" void kernel_launch(void* const* d_in, const int* in_sizes, int n_in,
                              void* d_out, int out_size, void* d_ws, size_t ws_size,
                              hipStream_t stream) {
  const float* x     = (const float*)d_in[0];  // [B][D]
  const float* W     = (const float*)d_in[1];  // [H][D]
  const float* b_enc = (const float*)d_in[2];  // [H]
  const float* act0b = (const float*)d_in[3];  // [H]
  const float* act3b = (const float*)d_in[4];  // [D]
  const float* cw    = (const float*)d_in[5];  // [L][H]

  float* out0 = (float*)d_out;              // output        [B][D]
  float* cls  = out0 + (size_t)Bn * Dn;     // classification[B][L]
  float* zout = cls + (size_t)Bn * Ln;      // z             [B][H]

  // Workspace layout (~6.8 MB).
  char* ws = (char*)d_ws;
  uint64_t* xbT    = (uint64_t*)ws; ws += (size_t)XW * Bn * 8;  // 2.62 MB [XW][Bn]
  uint64_t* wbits  = (uint64_t*)ws; ws += (size_t)Hn * XW * 8;  // 1.28 MB [Hn][XW]
  uint64_t* wtbits = (uint64_t*)ws; ws += (size_t)Dn * ZW * 8;  // 1.28 MB [Dn][ZW]
  uint64_t* zbT    = (uint64_t*)ws; ws += (size_t)ZW * Bn * 8;  // 1.05 MB [ZW][Bn]
  float*    fwT    = (float*)ws;    ws += (size_t)Hn * 64 * 4;  // 0.51 MB

  {  // x -> xbT (transposed: word-major)
    long long waves = (long long)Bn * (XW / 4);
    k_pack_rows4<<<(int)((waves * 64 + 255) / 256), 256, 0, stream>>>(
        x, xbT, Bn, Dn, XW, Bn, 1);
  }
  {  // W -> wbits (row-major)
    long long waves = (long long)Hn * (XW / 4);
    k_pack_rows4<<<(int)((waves * 64 + 255) / 256), 256, 0, stream>>>(
        W, wbits, Hn, Dn, XW, 1, XW);
  }
  {  // W columns -> wtbits
    long long waves = (long long)ZW * Dn;
    k_pack_wcols<<<(int)((waves * 64 + 255) / 256), 256, 0, stream>>>(W, wtbits);
  }
  k_pack_fwT<<<(Hn * 64 + 255) / 256, 256, 0, stream>>>(cw, fwT);
  k_zero<<<(Bn * Ln + 255) / 256, 256, 0, stream>>>(cls, Bn * Ln);

  dim3 g1((Hn + 255) / 256, Bn / 16);
  k_enc<<<g1, 256, 0, stream>>>(xbT, wbits, b_enc, act0b, zout, zbT);

  {  // waves = (Bn/4) * 16
    long long waves = (long long)(Bn / 4) * 16;
    k_cls<<<(int)((waves * 64 + 255) / 256), 256, 0, stream>>>(zout, fwT, cls);
  }

  dim3 g2((Dn + 255) / 256, Bn / 16);
  k_dec<<<g2, 256, 0, stream>>>(zbT, wtbits, act3b, out0);
}